// Round 6
// baseline (520.339 us; speedup 1.0000x reference)
//
#include <hip/hip_runtime.h>
#include <math.h>

// Problem constants (match reference)
constexpr int B = 128;
constexpr int N = 512;
constexpr int DEG = 8;
constexpr int D = 128;
constexpr int E = B * N * DEG;         // 524288
constexpr int EPG = N * DEG;           // 4096 edges per graph
constexpr int NN = B * N;              // 65536 total nodes
constexpr int K1 = 410;                // ceil(0.8*512)
constexpr int K2 = 328;                // ceil(0.8*410)
constexpr int PADDEG = 16;             // fixed-degree padding for gather

typedef __attribute__((ext_vector_type(8))) short short8;
typedef __attribute__((ext_vector_type(4))) float f32x4;

__device__ __forceinline__ unsigned short f2bf(float f) {
    unsigned int u = __float_as_uint(f);
    unsigned int r = (u + 0x7fffu + ((u >> 16) & 1u)) >> 16;   // RNE
    return (unsigned short)r;
}
__device__ __forceinline__ float bf2f(unsigned short h) {
    return __uint_as_float(((unsigned int)h) << 16);
}

// ---------------------------------------------------------------------------
// Weight prep: W[k][n] fp32 -> W^T[n][k] split into bf16 hi/lo.
// wt layout: matrix m at wt + m*32768; hi at +0 (16384), lo at +16384.
// 256 blocks (m = bid>>6), one element per thread.
// ---------------------------------------------------------------------------
__global__ __launch_bounds__(256) void k_prepw(const float* __restrict__ W0,
                                               const float* __restrict__ W1,
                                               const float* __restrict__ W2,
                                               const float* __restrict__ W3,
                                               unsigned short* __restrict__ wt) {
    const float* Ws[4] = {W0, W1, W2, W3};
    const int m = blockIdx.x >> 6;
    const int idx = (blockIdx.x & 63) * 256 + threadIdx.x;   // 0..16383
    const float* src = Ws[m];
    unsigned short* dH = wt + (size_t)m * 32768;
    unsigned short* dL = dH + 16384;
    int kk = idx >> 7, n = idx & 127;
    float v = src[idx];                 // [k][n] row-major
    unsigned short h = f2bf(v);
    unsigned short l = f2bf(v - bf2f(h));
    dH[n * 128 + kk] = h;               // transposed [n][k]
    dL[n * 128 + kk] = l;
}

// ---------------------------------------------------------------------------
// CSR build: per-graph counting sort of edges by dst. One block per graph.
// Variable CSR (coff/ccnt/csrc) + padded fixed-degree(16) csrcp
// (pad slots = self-index; fused gather skips them via deg guard).
// ---------------------------------------------------------------------------
__global__ __launch_bounds__(512) void k_csr2(const int* __restrict__ ei,
                                              int* __restrict__ coff,
                                              int* __restrict__ ccnt,
                                              int* __restrict__ csrc,
                                              int* __restrict__ csrcp) {
    __shared__ int cnt[512];
    __shared__ int sa[512];
    __shared__ int offs[512];
    __shared__ int cur[512];
    const int g = blockIdx.x, t = threadIdx.x;
    const int base = g * N;
    const int* srcs = ei + g * EPG;          // ei[0:E] = src
    const int* dsts = ei + E + g * EPG;      // ei[E:2E] = dst
    {
        const int n = base + t;
        int4 self = make_int4(n, n, n, n);
        #pragma unroll
        for (int k4 = 0; k4 < PADDEG / 4; ++k4)
            *(int4*)&csrcp[(size_t)n * PADDEG + k4 * 4] = self;
    }
    cnt[t] = 0;
    __syncthreads();
    #pragma unroll
    for (int e = t; e < EPG; e += 512)
        atomicAdd(&cnt[dsts[e] - base], 1);
    __syncthreads();
    int v = cnt[t];
    sa[t] = v;
    __syncthreads();
    for (int d = 1; d < 512; d <<= 1) {
        int add = (t >= d) ? sa[t - d] : 0;
        __syncthreads();
        sa[t] += add;
        __syncthreads();
    }
    const int excl = sa[t] - v;              // exclusive prefix within graph
    offs[t] = excl;
    cur[t] = excl;
    coff[base + t] = g * EPG + excl;
    ccnt[base + t] = v;
    __syncthreads();
    #pragma unroll
    for (int e = t; e < EPG; e += 512) {
        int d = dsts[e] - base;
        int pos = atomicAdd(&cur[d], 1);     // graph-global slot
        int s = srcs[e];
        csrc[g * EPG + pos] = s;
        int lpos = pos - offs[d];            // node-local slot
        if (lpos < PADDEG) csrcp[(size_t)(base + d) * PADDEG + lpos] = s;
    }
}

// ---------------------------------------------------------------------------
// FUSED gather + MFMA conv GEMM (bf16 hi/lo split, 3-product):
//   out = relu( (feat.*gate) @ W0 + agg(feat.*gate) @ W1 + bias )
//   sun[row] = out[row,:] . pvec
// Phase 0 A = self feature row (gated); phase 1 A = neighbor aggregate,
// GATHERED ON THE FLY per 32-k chunk (thread owns half a row: 16 k's in
// registers; neighbor idx/gates preloaded once). No agg array, no separate
// gather kernel. BM=BN=128, BK=32; 256 thr = 4 waves, each 64x64 via 4x4
// tiles of mfma_f32_16x16x32_bf16. XCD swizzle: a graph's 4 row-blocks share
// bid&7 so its 256KB feat chunk stays in one XCD's L2.
// ---------------------------------------------------------------------------
__global__ __launch_bounds__(256, 2) void k_fused(const float* __restrict__ feat,
                                                  const float* __restrict__ gate,
                                                  const int* __restrict__ coff,
                                                  const int* __restrict__ ccnt,
                                                  const int* __restrict__ csrc,
                                                  const int* __restrict__ csrcp,
                                                  const unsigned short* __restrict__ W0t,
                                                  const unsigned short* __restrict__ W1t,
                                                  const float* __restrict__ bias,
                                                  const float* __restrict__ pvec,
                                                  float* __restrict__ out,
                                                  float* __restrict__ sun) {
    __shared__ unsigned short AsH[128 * 40], AsL[128 * 40];
    __shared__ unsigned short BsH[128 * 40], BsL[128 * 40];
    __shared__ float red[128 * 33];
    const int t = threadIdx.x;
    const int bid = blockIdx.x;
    const int xcd = bid & 7, j = bid >> 3;           // j: 0..63
    const int g = (j & 15) * 8 + xcd;                // graph, fixed per xcd
    const int chunkRow = j >> 4;                     // 0..3
    const int r0 = g * N + chunkRow * 128;
    const int w = t >> 6, lane = t & 63;
    const int lr = lane & 15, kg = (lane >> 4) * 8;
    const int wm = (w >> 1) * 64, wn = (w & 1) * 64;
    const int arow = t >> 1, kb = (t & 1) * 16;      // A staging: half-row each
    const int node = r0 + arow;

    // --- per-row gather state (loaded once) ---
    const int deg = ccnt[node];
    const float ga = gate ? gate[node] : 1.0f;       // row's own gate (phase 0)
    int idx[PADDEG];
    *(int4*)&idx[0]  = *(const int4*)&csrcp[(size_t)node * PADDEG + 0];
    *(int4*)&idx[4]  = *(const int4*)&csrcp[(size_t)node * PADDEG + 4];
    *(int4*)&idx[8]  = *(const int4*)&csrcp[(size_t)node * PADDEG + 8];
    *(int4*)&idx[12] = *(const int4*)&csrcp[(size_t)node * PADDEG + 12];
    float wk[PADDEG];
    #pragma unroll
    for (int nb = 0; nb < PADDEG; ++nb)
        wk[nb] = (nb < deg) ? (gate ? gate[idx[nb]] : 1.0f) : 0.0f;

    f32x4 acc[4][4];
    #pragma unroll
    for (int mt = 0; mt < 4; ++mt)
        #pragma unroll
        for (int nt = 0; nt < 4; ++nt)
            acc[mt][nt] = (f32x4)(0.f);

    for (int phase = 0; phase < 2; ++phase) {
        const unsigned short* WH = phase ? W1t : W0t;
        const unsigned short* WL = WH + 16384;
        for (int c = 0; c < 4; ++c) {
            const int k0 = c * 32;
            __syncthreads();                 // previous chunk fully consumed
            // --- A source: 16 fp32 values for (row=arow, k=k0+kb..+16)
            float vals[16];
            if (phase == 0) {
                const float* fp = &feat[(size_t)node * D + k0 + kb];
                #pragma unroll
                for (int i = 0; i < 4; ++i) {
                    float4 v = ((const float4*)fp)[i];
                    vals[i * 4 + 0] = v.x * ga; vals[i * 4 + 1] = v.y * ga;
                    vals[i * 4 + 2] = v.z * ga; vals[i * 4 + 3] = v.w * ga;
                }
            } else {
                #pragma unroll
                for (int i = 0; i < 16; ++i) vals[i] = 0.f;
                #pragma unroll
                for (int nb = 0; nb < PADDEG; ++nb) {
                    if (nb < deg) {
                        const float* fp = &feat[(size_t)idx[nb] * D + k0 + kb];
                        const float wn_ = wk[nb];
                        #pragma unroll
                        for (int i = 0; i < 4; ++i) {
                            float4 v = ((const float4*)fp)[i];
                            vals[i * 4 + 0] = fmaf(v.x, wn_, vals[i * 4 + 0]);
                            vals[i * 4 + 1] = fmaf(v.y, wn_, vals[i * 4 + 1]);
                            vals[i * 4 + 2] = fmaf(v.z, wn_, vals[i * 4 + 2]);
                            vals[i * 4 + 3] = fmaf(v.w, wn_, vals[i * 4 + 3]);
                        }
                    }
                }
                if (deg > PADDEG) {          // rare tail
                    const int start = coff[node];
                    for (int k = PADDEG; k < deg; ++k) {
                        int ix = csrc[start + k];
                        float gt = gate ? gate[ix] : 1.0f;
                        const float* fp = &feat[(size_t)ix * D + k0 + kb];
                        #pragma unroll
                        for (int i = 0; i < 4; ++i) {
                            float4 v = ((const float4*)fp)[i];
                            vals[i * 4 + 0] = fmaf(v.x, gt, vals[i * 4 + 0]);
                            vals[i * 4 + 1] = fmaf(v.y, gt, vals[i * 4 + 1]);
                            vals[i * 4 + 2] = fmaf(v.z, gt, vals[i * 4 + 2]);
                            vals[i * 4 + 3] = fmaf(v.w, gt, vals[i * 4 + 3]);
                        }
                    }
                }
            }
            // --- split to hi/lo bf16, write LDS [row][k] stride 40
            unsigned int ph[8], pl[8];
            #pragma unroll
            for (int jj = 0; jj < 8; ++jj) {
                unsigned int h0 = f2bf(vals[2 * jj]), h1 = f2bf(vals[2 * jj + 1]);
                ph[jj] = h0 | (h1 << 16);
                unsigned int l0 = f2bf(vals[2 * jj] - bf2f((unsigned short)h0));
                unsigned int l1 = f2bf(vals[2 * jj + 1] - bf2f((unsigned short)h1));
                pl[jj] = l0 | (l1 << 16);
            }
            *(int4*)&AsH[arow * 40 + kb]     = make_int4(ph[0], ph[1], ph[2], ph[3]);
            *(int4*)&AsH[arow * 40 + kb + 8] = make_int4(ph[4], ph[5], ph[6], ph[7]);
            *(int4*)&AsL[arow * 40 + kb]     = make_int4(pl[0], pl[1], pl[2], pl[3]);
            *(int4*)&AsL[arow * 40 + kb + 8] = make_int4(pl[4], pl[5], pl[6], pl[7]);
            // --- B stage: copy pre-split W^T[n][k] chunk, stride 40
            {
                const int part = t & 3;
                #pragma unroll
                for (int rep = 0; rep < 2; ++rep) {
                    const int n = (t >> 2) + rep * 64;
                    *(int4*)&BsH[n * 40 + part * 8] = *(const int4*)&WH[n * 128 + k0 + part * 8];
                    *(int4*)&BsL[n * 40 + part * 8] = *(const int4*)&WL[n * 128 + k0 + part * 8];
                }
            }
            __syncthreads();
            // --- fragments + MFMA
            short8 aH[4], aL[4], bH[4], bL[4];
            #pragma unroll
            for (int mt = 0; mt < 4; ++mt) {
                aH[mt] = *(const short8*)&AsH[(wm + mt * 16 + lr) * 40 + kg];
                aL[mt] = *(const short8*)&AsL[(wm + mt * 16 + lr) * 40 + kg];
            }
            #pragma unroll
            for (int nt = 0; nt < 4; ++nt) {
                bH[nt] = *(const short8*)&BsH[(wn + nt * 16 + lr) * 40 + kg];
                bL[nt] = *(const short8*)&BsL[(wn + nt * 16 + lr) * 40 + kg];
            }
            #pragma unroll
            for (int mt = 0; mt < 4; ++mt)
                #pragma unroll
                for (int nt = 0; nt < 4; ++nt) {
                    acc[mt][nt] = __builtin_amdgcn_mfma_f32_16x16x32_bf16(aH[mt], bH[nt], acc[mt][nt], 0, 0, 0);
                    acc[mt][nt] = __builtin_amdgcn_mfma_f32_16x16x32_bf16(aH[mt], bL[nt], acc[mt][nt], 0, 0, 0);
                    acc[mt][nt] = __builtin_amdgcn_mfma_f32_16x16x32_bf16(aL[mt], bH[nt], acc[mt][nt], 0, 0, 0);
                }
        }
    }
    // --- Epilogue: bias + relu + store + score partials
    float bb[4], pv[4];
    #pragma unroll
    for (int nt = 0; nt < 4; ++nt) {
        bb[nt] = bias[wn + nt * 16 + lr];
        pv[nt] = pvec[wn + nt * 16 + lr];
    }
    #pragma unroll
    for (int mt = 0; mt < 4; ++mt) {
        #pragma unroll
        for (int r = 0; r < 4; ++r) {
            const int rowl = wm + mt * 16 + (lane >> 4) * 4 + r;
            const int row = r0 + rowl;
            float part = 0.f;
            #pragma unroll
            for (int nt = 0; nt < 4; ++nt) {
                float v = acc[mt][nt][r] + bb[nt];
                v = fmaxf(v, 0.f);
                out[(size_t)row * D + wn + nt * 16 + lr] = v;
                part = fmaf(v, pv[nt], part);
            }
            red[rowl * 33 + (w & 1) * 16 + lr] = part;   // unique slot per lane
        }
    }
    __syncthreads();
    if (t < 128) {
        float s = 0.f;
        #pragma unroll
        for (int jj = 0; jj < 32; ++jj) s += red[t * 33 + jj];
        sun[r0 + t] = s;
    }
}

// ---------------------------------------------------------------------------
// Fused per-graph TopK + readout, 2 blocks per graph (feature halves).
// TopK rank matches jax.lax.top_k stable order; gate = tanh(s/||p||)*keep.
// Both blocks of a graph compute identical gates (benign duplicate writes).
// ---------------------------------------------------------------------------
__global__ __launch_bounds__(1024) void k_topk_readout(const float* __restrict__ sun,
                                                       const float* __restrict__ p,
                                                       const float* __restrict__ prevmask,
                                                       int K, float invK,
                                                       const float* __restrict__ h,
                                                       float* __restrict__ gate,
                                                       float* __restrict__ mask,
                                                       float* __restrict__ xout) {
    __shared__ float ls[512];
    __shared__ float lg[512];
    __shared__ float lm[512];
    __shared__ float red[128];
    __shared__ float smax[16][64];
    __shared__ float ssum[16][64];
    __shared__ float norm_s;
    const int bid = blockIdx.x;
    const int g = bid >> 1, half = bid & 1;
    const int t = threadIdx.x;
    if (t < 512) {
        const int n = g * N + t;
        float s = sun[n];
        if (prevmask && prevmask[n] == 0.0f) s = -INFINITY;
        ls[t] = s;
    }
    if (t < 128) { float pvv = p[t]; red[t] = pvv * pvv; }
    __syncthreads();
    if (t < 64) red[t] += red[t + 64];
    __syncthreads();
    if (t < 32) red[t] += red[t + 32];
    __syncthreads();
    if (t == 0) {
        float s = 0.f;
        #pragma unroll
        for (int i = 0; i < 32; ++i) s += red[i];
        norm_s = sqrtf(s);
    }
    __syncthreads();
    if (t < 512) {
        const float s = ls[t];
        int cnt = 0;
        for (int jj = 0; jj < 512; ++jj) {
            float sj = ls[jj];
            cnt += (sj > s || (sj == s && jj < t)) ? 1 : 0;
        }
        const bool keep = cnt < K;
        const float gv = keep ? tanhf(s / norm_s) : 0.0f;
        const float mv = keep ? 1.0f : 0.0f;
        lg[t] = gv; lm[t] = mv;
        gate[g * N + t] = gv; mask[g * N + t] = mv;
    }
    __syncthreads();
    const int f = half * 64 + (t & 63), sub = t >> 6;   // 16 subsets x 64 feats
    float vmax = -INFINITY, vsum = 0.f;
    for (int nl = sub; nl < N; nl += 16) {
        const float v = h[(size_t)(g * N + nl) * D + f] * lg[nl];
        vsum += v;
        if (lm[nl] != 0.f) vmax = fmaxf(vmax, v);
    }
    smax[sub][t & 63] = vmax;
    ssum[sub][t & 63] = vsum;
    __syncthreads();
    if (t < 64) {
        float m = smax[0][t], s = ssum[0][t];
        #pragma unroll
        for (int k = 1; k < 16; ++k) { m = fmaxf(m, smax[k][t]); s += ssum[k][t]; }
        xout[g * 256 + half * 64 + t] = m;
        xout[g * 256 + 128 + half * 64 + t] = s * invK;
    }
}

// ---------------------------------------------------------------------------
// MLP head. One block (128 threads) per graph.
// ---------------------------------------------------------------------------
__global__ __launch_bounds__(128) void k_mlp(const float* __restrict__ X1,
                                             const float* __restrict__ X2,
                                             const float* __restrict__ lw1,
                                             const float* __restrict__ lb1,
                                             const float* __restrict__ lw2,
                                             const float* __restrict__ lb2,
                                             const float* __restrict__ lw3,
                                             const float* __restrict__ lb3,
                                             float* __restrict__ out) {
    __shared__ float z[256];
    __shared__ float o1[128];
    __shared__ float o2p[64];
    const int g = blockIdx.x, t = threadIdx.x;
    z[t] = X1[g * 256 + t] + X2[g * 256 + t];
    z[t + 128] = X1[g * 256 + 128 + t] + X2[g * 256 + 128 + t];
    __syncthreads();
    float a = lb1[t];
    for (int i = 0; i < 256; ++i) a = fmaf(z[i], lw1[i * 128 + t], a);
    o1[t] = fmaxf(a, 0.f);
    __syncthreads();
    if (t < 64) {
        float b = lb2[t];
        for (int i = 0; i < 128; ++i) b = fmaf(o1[i], lw2[i * 64 + t], b);
        o2p[t] = fmaxf(b, 0.f) * lw3[t];
    }
    __syncthreads();
    if (t == 0) {
        float sacc = lb3[0];
        for (int i = 0; i < 64; ++i) sacc += o2p[i];
        out[g] = 1.f / (1.f + expf(-sacc));
    }
}

// ---------------------------------------------------------------------------
extern "C" void kernel_launch(void* const* d_in, const int* in_sizes, int n_in,
                              void* d_out, int out_size, void* d_ws, size_t ws_size,
                              hipStream_t stream) {
    const float* x    = (const float*)d_in[0];
    const int*   ei   = (const int*)d_in[1];
    const float* W1r  = (const float*)d_in[2];
    const float* W1n  = (const float*)d_in[3];
    const float* b1   = (const float*)d_in[4];
    const float* p1   = (const float*)d_in[5];
    const float* W2r  = (const float*)d_in[6];
    const float* W2n  = (const float*)d_in[7];
    const float* b2   = (const float*)d_in[8];
    const float* p2   = (const float*)d_in[9];
    const float* lw1  = (const float*)d_in[10];
    const float* lb1  = (const float*)d_in[11];
    const float* lw2  = (const float*)d_in[12];
    const float* lb2  = (const float*)d_in[13];
    const float* lw3  = (const float*)d_in[14];
    const float* lb3  = (const float*)d_in[15];
    float* out = (float*)d_out;

    // Workspace layout (~80 MB total)
    char* w = (char*)d_ws;
    float* h1  = (float*)w; w += (size_t)NN * D * 4;
    float* h2  = (float*)w; w += (size_t)NN * D * 4;
    int* coff  = (int*)w;   w += (size_t)NN * 4;
    int* ccnt  = (int*)w;   w += (size_t)NN * 4;
    int* csrc  = (int*)w;   w += (size_t)E * 4;
    int* csrcp = (int*)w;   w += (size_t)NN * PADDEG * 4;
    unsigned short* wt = (unsigned short*)w; w += (size_t)4 * 2 * 16384 * 2;  // 4 mats x hi/lo
    float* sun = (float*)w; w += (size_t)NN * 4;
    float* g1  = (float*)w; w += (size_t)NN * 4;
    float* m1  = (float*)w; w += (size_t)NN * 4;
    float* g2  = (float*)w; w += (size_t)NN * 4;
    float* m2  = (float*)w; w += (size_t)NN * 4;
    float* X1  = (float*)w; w += (size_t)B * 256 * 4;
    float* X2  = (float*)w; w += (size_t)B * 256 * 4;

    const unsigned short* wt1r = wt;                 // slot 0: W1r
    const unsigned short* wt1n = wt + 1 * 32768;     // slot 1: W1n
    const unsigned short* wt2r = wt + 2 * 32768;     // slot 2: W2r
    const unsigned short* wt2n = wt + 3 * 32768;     // slot 3: W2n

    // One-time prep: weights split/transpose + CSR build
    k_prepw<<<256, 256, 0, stream>>>(W1r, W1n, W2r, W2n, wt);
    k_csr2<<<B, 512, 0, stream>>>(ei, coff, ccnt, csrc, csrcp);

    // conv1: h1 = relu(x@W1r + agg(x)@W1n + b1); s1 = h1.p1
    k_fused<<<NN / 128, 256, 0, stream>>>(x, nullptr, coff, ccnt, csrc, csrcp,
                                          wt1r, wt1n, b1, p1, h1, sun);
    k_topk_readout<<<2 * B, 1024, 0, stream>>>(sun, p1, nullptr, K1, 1.0f / (float)K1, h1, g1, m1, X1);

    // conv2: h2 = relu((h1.*g1)@W2r + agg(h1.*g1)@W2n + b2); s2 = h2.p2
    k_fused<<<NN / 128, 256, 0, stream>>>(h1, g1, coff, ccnt, csrc, csrcp,
                                          wt2r, wt2n, b2, p2, h2, sun);
    k_topk_readout<<<2 * B, 1024, 0, stream>>>(sun, p2, m1, K2, 1.0f / (float)K2, h2, g2, m2, X2);

    // MLP head
    k_mlp<<<B, 128, 0, stream>>>(X1, X2, lw1, lb1, lw2, lb2, lw3, lb3, out);
}